// Round 10
// baseline (1088.676 us; speedup 1.0000x reference)
//
#include <hip/hip_runtime.h>

#define EPSV 1e-6f
#define NBMAX 512      // per-branch coarse buckets (128 nodes each) — N <= 65536
#define ECHUNK 4096    // edges per block in P1/P3

typedef float nf4 __attribute__((ext_vector_type(4)));

// non-temporal float4 load/store (builtin needs native clang vector, not HIP_vector_type)
__device__ __forceinline__ float4 ntload4(const float4* p) {
    nf4 v = __builtin_nontemporal_load(reinterpret_cast<const nf4*>(p));
    return make_float4(v.x, v.y, v.z, v.w);
}
__device__ __forceinline__ void ntstore4(float4 v, float4* p) {
    nf4 q = {v.x, v.y, v.z, v.w};
    __builtin_nontemporal_store(q, reinterpret_cast<nf4*>(p));
}

// ---------------- P1: coarse histogram by dst>>7, both branches (blockIdx.y) ----------------
__global__ __launch_bounds__(256) void coarse_hist_kernel(
    const int* __restrict__ ei1, const int* __restrict__ ei2,
    int* __restrict__ chist, int E, int NB) {
    __shared__ int lh[NBMAX];
    int t = threadIdx.x;
    int branch = blockIdx.y;
    const int* dst = (branch ? ei2 : ei1) + E;
    for (int i = t; i < NB; i += 256) lh[i] = 0;
    __syncthreads();
    int base = blockIdx.x * ECHUNK;
    int end = min(base + ECHUNK, E);
    for (int i = base + t; i < end; i += 256) atomicAdd(&lh[dst[i] >> 7], 1);
    __syncthreads();
    int* gh = chist + branch * NB;
    for (int i = t; i < NB; i += 256)
        if (lh[i]) atomicAdd(&gh[i], lh[i]);
}

// ---------------- P2: scan of combined hist (NB2 <= 1024), 1 block, 4/thread ----------------
__global__ __launch_bounds__(256) void coarse_scan_kernel(
    const int* __restrict__ chist, int* __restrict__ cstarts,
    int* __restrict__ ccur, int NB2) {
    __shared__ int wt[4];
    int t = threadIdx.x, lane = t & 63, w = t >> 6;
    int base = t * 4;
    int v[4];
    int run = 0;
#pragma unroll
    for (int j = 0; j < 4; ++j) {
        v[j] = (base + j < NB2) ? chist[base + j] : 0;
        run += v[j];
    }
    int tot = run, inc = tot;
#pragma unroll
    for (int off = 1; off < 64; off <<= 1) {
        int y = __shfl_up(inc, off);
        if (lane >= off) inc += y;
    }
    if (lane == 63) wt[w] = inc;
    __syncthreads();
    int pre = 0;
    for (int ww = 0; ww < w; ++ww) pre += wt[ww];
    int excl = pre + inc - tot;
    int run2 = 0;
#pragma unroll
    for (int j = 0; j < 4; ++j) {
        if (base + j < NB2) { cstarts[base + j] = excl + run2; ccur[base + j] = excl + run2; }
        run2 += v[j];
    }
    if (t == 0) cstarts[NB2] = wt[0] + wt[1] + wt[2] + wt[3];
}

// ---------------- P3: partition edges into coarse buckets (packed src|dstlow) ----------------
__global__ __launch_bounds__(256) void partition_kernel(
    const int* __restrict__ ei1, const int* __restrict__ ei2,
    int* __restrict__ ccur, unsigned int* __restrict__ epack, int E, int NB) {
    __shared__ int lh[NBMAX];
    __shared__ int lbase[NBMAX];
    int t = threadIdx.x;
    int branch = blockIdx.y;
    const int* src = branch ? ei2 : ei1;
    const int* dst = src + E;
    for (int i = t; i < NB; i += 256) lh[i] = 0;
    __syncthreads();
    int base = blockIdx.x * ECHUNK;
    int end = min(base + ECHUNK, E);
    for (int i = base + t; i < end; i += 256) atomicAdd(&lh[dst[i] >> 7], 1);
    __syncthreads();
    int* gc = ccur + branch * NB;
    for (int i = t; i < NB; i += 256) {
        int c = lh[i];
        lbase[i] = c ? atomicAdd(&gc[i], c) : 0;
        lh[i] = 0;   // reuse as local cursor
    }
    __syncthreads();
    for (int i = base + t; i < end; i += 256) {
        int d = dst[i];
        int b = d >> 7;
        int pos = lbase[b] + atomicAdd(&lh[b], 1);
        epack[pos] = (unsigned)src[i] | ((unsigned)(d & 127) << 16);
    }
}

// ---------------- P4: fine counting sort within bucket; emit esrc, starts, dinv ----------------
__global__ __launch_bounds__(256) void fine_sort_kernel(
    const unsigned int* __restrict__ epack, const int* __restrict__ cstarts,
    int* __restrict__ esrc, int* __restrict__ starts, float* __restrict__ dinv,
    int N, int NB, int NB2) {
    __shared__ int fh[128];
    __shared__ int fex[128];
    int b = blockIdx.x, t = threadIdx.x;
    int branch = (b >= NB) ? 1 : 0;
    int soff = branch * N;
    int s0 = cstarts[b], s1 = cstarts[b + 1];
    if (t < 128) fh[t] = 0;
    __syncthreads();
    for (int i = s0 + t; i < s1; i += 256) atomicAdd(&fh[epack[i] >> 16], 1);
    __syncthreads();
    if (t < 64) {
        int a = fh[t * 2], c = fh[t * 2 + 1];
        int tot = a + c, inc = tot;
#pragma unroll
        for (int off = 1; off < 64; off <<= 1) {
            int y = __shfl_up(inc, off);
            if (t >= off) inc += y;
        }
        int excl = inc - tot;
        fex[t * 2] = excl;
        fex[t * 2 + 1] = excl + a;
    }
    __syncthreads();
    int nb0 = (b - branch * NB) << 7;
    if (t < 128) {
        int node_local = nb0 + t;
        if (node_local < N) {
            int gnode = node_local + soff;
            starts[gnode] = s0 + fex[t];
            dinv[gnode] = 1.0f / sqrtf((float)fh[t] + 1.0f);
        }
    }
    if (b == NB2 - 1 && t == 0) starts[2 * N] = s1;
    __syncthreads();
    if (t < 128) fh[t] = fex[t];
    __syncthreads();
    for (int i = s0 + t; i < s1; i += 256) {
        unsigned p = epack[i];
        int f = (int)(p >> 16);
        int pos = s0 + atomicAdd(&fh[f], 1);
        esrc[pos] = (int)(p & 0xFFFFu) + soff;
    }
}

// ---------------- device: one node's gather (32 lanes per node, 8-way MLP) ----------------
// esrc loads and C store are non-temporal (single-touch streams): keep L2 for H rows.
__device__ __forceinline__ void gather_one(
    const float4* __restrict__ H4, const int* __restrict__ esrc,
    const int* __restrict__ starts, const float* __restrict__ dinv,
    float4* __restrict__ C4, int node, int lane) {
    float4 a0 = H4[node * 32 + lane];
    float4 a1 = make_float4(0.f, 0.f, 0.f, 0.f);
    float4 a2 = make_float4(0.f, 0.f, 0.f, 0.f);
    float4 a3 = make_float4(0.f, 0.f, 0.f, 0.f);
    int s0 = starts[node], s1 = starts[node + 1];
    int i = s0;
    for (; i + 8 <= s1; i += 8) {
        int e0 = __builtin_nontemporal_load(&esrc[i]);
        int e1 = __builtin_nontemporal_load(&esrc[i + 1]);
        int e2 = __builtin_nontemporal_load(&esrc[i + 2]);
        int e3 = __builtin_nontemporal_load(&esrc[i + 3]);
        int e4 = __builtin_nontemporal_load(&esrc[i + 4]);
        int e5 = __builtin_nontemporal_load(&esrc[i + 5]);
        int e6 = __builtin_nontemporal_load(&esrc[i + 6]);
        int e7 = __builtin_nontemporal_load(&esrc[i + 7]);
        float4 v0 = H4[e0 * 32 + lane];
        float4 v1 = H4[e1 * 32 + lane];
        float4 v2 = H4[e2 * 32 + lane];
        float4 v3 = H4[e3 * 32 + lane];
        float4 v4 = H4[e4 * 32 + lane];
        float4 v5 = H4[e5 * 32 + lane];
        float4 v6 = H4[e6 * 32 + lane];
        float4 v7 = H4[e7 * 32 + lane];
        a0.x += v0.x; a0.y += v0.y; a0.z += v0.z; a0.w += v0.w;
        a1.x += v1.x; a1.y += v1.y; a1.z += v1.z; a1.w += v1.w;
        a2.x += v2.x; a2.y += v2.y; a2.z += v2.z; a2.w += v2.w;
        a3.x += v3.x; a3.y += v3.y; a3.z += v3.z; a3.w += v3.w;
        a0.x += v4.x; a0.y += v4.y; a0.z += v4.z; a0.w += v4.w;
        a1.x += v5.x; a1.y += v5.y; a1.z += v5.z; a1.w += v5.w;
        a2.x += v6.x; a2.y += v6.y; a2.z += v6.z; a2.w += v6.w;
        a3.x += v7.x; a3.y += v7.y; a3.z += v7.z; a3.w += v7.w;
    }
    for (; i + 4 <= s1; i += 4) {
        int e0 = __builtin_nontemporal_load(&esrc[i]);
        int e1 = __builtin_nontemporal_load(&esrc[i + 1]);
        int e2 = __builtin_nontemporal_load(&esrc[i + 2]);
        int e3 = __builtin_nontemporal_load(&esrc[i + 3]);
        float4 v0 = H4[e0 * 32 + lane];
        float4 v1 = H4[e1 * 32 + lane];
        float4 v2 = H4[e2 * 32 + lane];
        float4 v3 = H4[e3 * 32 + lane];
        a0.x += v0.x; a0.y += v0.y; a0.z += v0.z; a0.w += v0.w;
        a1.x += v1.x; a1.y += v1.y; a1.z += v1.z; a1.w += v1.w;
        a2.x += v2.x; a2.y += v2.y; a2.z += v2.z; a2.w += v2.w;
        a3.x += v3.x; a3.y += v3.y; a3.z += v3.z; a3.w += v3.w;
    }
    for (; i < s1; ++i) {
        float4 v = H4[__builtin_nontemporal_load(&esrc[i]) * 32 + lane];
        a0.x += v.x; a0.y += v.y; a0.z += v.z; a0.w += v.w;
    }
    a0.x += a1.x + a2.x + a3.x;
    a0.y += a1.y + a2.y + a3.y;
    a0.z += a1.z + a2.z + a3.z;
    a0.w += a1.w + a2.w + a3.w;
    float dd = dinv[node];
    a0.x *= dd; a0.y *= dd; a0.z *= dd; a0.w *= dd;
    ntstore4(a0, &C4[node * 32 + lane]);
}

// ---------------- device: one block's 64x128 GEMM tile, 512 threads, 4 rows/thread ----------------
// Staging loads and Y stores are non-temporal; W stays cached (reused).
template <bool PRE>
__device__ __forceinline__ void gemm_block(
    float* Xs, const float* __restrict__ X, const float* __restrict__ W,
    const float* __restrict__ preb, const float* __restrict__ dinvL,
    float* __restrict__ YL, int bidx, int t, int M) {
    int row0 = bidx * 64;
    for (int i = t; i < 64 * 32; i += 512) {
        int r = i >> 5;
        int gr = row0 + r;
        float4 v = make_float4(0.f, 0.f, 0.f, 0.f);
        if (gr < M) {
            v = ntload4(&reinterpret_cast<const float4*>(X)[gr * 32 + (i & 31)]);
            if (PRE) {
                float4 bb = reinterpret_cast<const float4*>(preb)[i & 31];
                v.x = fmaxf(v.x + bb.x, 0.f);
                v.y = fmaxf(v.y + bb.y, 0.f);
                v.z = fmaxf(v.z + bb.z, 0.f);
                v.w = fmaxf(v.w + bb.w, 0.f);
            }
        }
        reinterpret_cast<float4*>(Xs)[i] = v;
    }
    __syncthreads();
    int cg = t & 31;    // col group: cols 4*cg..4*cg+3
    int rg = t >> 5;    // 0..15, rows rg*4..rg*4+3
    float acc[4][4];
#pragma unroll
    for (int r = 0; r < 4; ++r) {
        acc[r][0] = 0.f; acc[r][1] = 0.f; acc[r][2] = 0.f; acc[r][3] = 0.f;
    }
    const float* xb = &Xs[rg * 4 * 128];
    const float4* W4 = reinterpret_cast<const float4*>(W);
#pragma unroll 4
    for (int k = 0; k < 128; ++k) {
        float4 wv = W4[k * 32 + cg];
#pragma unroll
        for (int r = 0; r < 4; ++r) {
            float xv = xb[r * 128 + k];
            acc[r][0] = fmaf(xv, wv.x, acc[r][0]);
            acc[r][1] = fmaf(xv, wv.y, acc[r][1]);
            acc[r][2] = fmaf(xv, wv.z, acc[r][2]);
            acc[r][3] = fmaf(xv, wv.w, acc[r][3]);
        }
    }
#pragma unroll
    for (int r = 0; r < 4; ++r) {
        int gr = row0 + rg * 4 + r;
        if (gr < M) {
            float s = dinvL[gr];
            float4 v = make_float4(acc[r][0] * s, acc[r][1] * s,
                                   acc[r][2] * s, acc[r][3] * s);
            ntstore4(v, &reinterpret_cast<float4*>(YL)[gr * 32 + cg]);
        }
    }
}

// ---------------- standalone GEMM (branch via blockIdx.y), 512 threads ----------------
template <bool PRE>
__global__ __launch_bounds__(512) void gemm128_kernel(
    const float* __restrict__ Xa, const float* __restrict__ Xb,
    const float* __restrict__ W, const float* __restrict__ preb,
    const float* __restrict__ dinv, float* __restrict__ Y, int M) {
    __shared__ float Xs[64 * 128];
    int branch = blockIdx.y;
    const float* X = branch ? Xb : Xa;
    int goff = branch * M;
    gemm_block<PRE>(Xs, X, W, preb, dinv + goff, Y + (size_t)goff * 128,
                    blockIdx.x, threadIdx.x, M);
}

// ---------------- standalone gather over node range [node0, node0+n) ----------------
__global__ __launch_bounds__(256) void gather_kernel(
    const float* __restrict__ H, const int* __restrict__ esrc,
    const int* __restrict__ starts, const float* __restrict__ dinv,
    float* __restrict__ C, int node0, int n) {
    int gid = blockIdx.x * blockDim.x + threadIdx.x;
    int node = node0 + (gid >> 5);
    int lane = gid & 31;
    if (node >= node0 + n) return;
    gather_one(reinterpret_cast<const float4*>(H), esrc, starts, dinv,
               reinterpret_cast<float4*>(C), node, lane);
}

// ---------------- combo: gather(branch X) ∥ gemm(branch Y), one 512-thread launch ----------------
// GEMM blocks first (few, long); gather blocks after (many, short).
// 32 KB LDS x 4 blocks x 512 thr = full 2048-thread occupancy even with LDS.
template <bool PRE>
__global__ __launch_bounds__(512) void combo_kernel(
    const float* __restrict__ B, const int* __restrict__ esrc,
    const int* __restrict__ starts, const float* __restrict__ dinv,
    float* __restrict__ C, int gnode0, int Ng,
    const float* __restrict__ Xg, const float* __restrict__ W,
    const float* __restrict__ preb, float* __restrict__ Y,
    int ynode0, int M, int nGemm) {
    __shared__ float Xs[64 * 128];
    int bid = blockIdx.x;
    int t = threadIdx.x;
    if (bid < nGemm) {
        gemm_block<PRE>(Xs, Xg, W, preb, dinv + ynode0, Y + (size_t)ynode0 * 128,
                        bid, t, M);
    } else {
        int gid = (bid - nGemm) * 512 + t;
        int node = gnode0 + (gid >> 5);
        int lane = gid & 31;
        if (node < gnode0 + Ng)
            gather_one(reinterpret_cast<const float4*>(B), esrc, starts, dinv,
                       reinterpret_cast<float4*>(C), node, lane);
    }
}

// ---------------- mean pool: run-length accumulate over sorted batch, both branches ----------------
__global__ void pool_kernel(const float* __restrict__ C, const int* __restrict__ batch1,
                            const int* __restrict__ batch2, float* __restrict__ pooled,
                            int N, int n2, int G) {
    int gid = blockIdx.x * blockDim.x + threadIdx.x;
    int grp = gid >> 5;
    int lane = gid & 31;
    int n0 = grp * 16;
    if (n0 >= n2) return;
    int nend = min(n0 + 16, n2);
    int branch = (n0 >= N) ? 1 : 0;
    const int* batch = branch ? batch2 : batch1;
    int boff = branch * N;
    float* pg = pooled + (size_t)branch * G * 128;
    const float4* C4 = reinterpret_cast<const float4*>(C);
    float4 acc = make_float4(0.f, 0.f, 0.f, 0.f);
    int gcur = batch[n0 - boff];
    for (int j = n0; j < nend; ++j) {
        int g = batch[j - boff];
        if (g != gcur) {
            atomicAdd(&pg[gcur * 128 + lane * 4 + 0], acc.x);
            atomicAdd(&pg[gcur * 128 + lane * 4 + 1], acc.y);
            atomicAdd(&pg[gcur * 128 + lane * 4 + 2], acc.z);
            atomicAdd(&pg[gcur * 128 + lane * 4 + 3], acc.w);
            acc = make_float4(0.f, 0.f, 0.f, 0.f);
            gcur = g;
        }
        float4 v = C4[j * 32 + lane];
        acc.x += v.x; acc.y += v.y; acc.z += v.z; acc.w += v.w;
    }
    atomicAdd(&pg[gcur * 128 + lane * 4 + 0], acc.x);
    atomicAdd(&pg[gcur * 128 + lane * 4 + 1], acc.y);
    atomicAdd(&pg[gcur * 128 + lane * 4 + 2], acc.z);
    atomicAdd(&pg[gcur * 128 + lane * 4 + 3], acc.w);
}

// ---------------- per-graph node count via binary search, both branches ----------------
__global__ void cnt_kernel(const int* __restrict__ batch1, const int* __restrict__ batch2,
                           float* __restrict__ cnt, int n, int G) {
    int g = blockIdx.x * blockDim.x + threadIdx.x;
    if (g >= 2 * G) return;
    int branch = (g >= G) ? 1 : 0;
    int gl = g - branch * G;
    const int* batch = branch ? batch2 : batch1;
    int lo = 0, hi = n;
    while (lo < hi) { int m = (lo + hi) >> 1; if (batch[m] < gl) lo = m + 1; else hi = m; }
    int lb = lo;
    hi = n;
    while (lo < hi) { int m = (lo + hi) >> 1; if (batch[m] <= gl) lo = m + 1; else hi = m; }
    cnt[g] = (float)(lo - lb);
}

// ---------------- final linear over 2G graphs ----------------
__global__ void final_kernel(const float* __restrict__ pooled, const float* __restrict__ cnt,
                             const float* __restrict__ b3, const float* __restrict__ Wlin,
                             const float* __restrict__ blin, float* __restrict__ e) {
    int g = blockIdx.x;
    int nidx = threadIdx.x;
    float inv = 1.0f / fmaxf(cnt[g], 1.0f);
    float acc = blin[nidx];
    for (int k = 0; k < 128; ++k) {
        float xk = fmaf(pooled[g * 128 + k], inv, b3[k]);
        acc = fmaf(xk, Wlin[k * 64 + nidx], acc);
    }
    e[g * 64 + nidx] = acc;
}

// ---------------- pairwise distance ----------------
__global__ void dist_kernel(const float* __restrict__ e1, const float* __restrict__ e2,
                            float* __restrict__ out, int G) {
    int g = blockIdx.x * blockDim.x + threadIdx.x;
    if (g >= G) return;
    float acc = 0.f;
    for (int j = 0; j < 64; ++j) {
        float d = e1[g * 64 + j] - e2[g * 64 + j] + EPSV;
        acc = fmaf(d, d, acc);
    }
    out[g] = sqrtf(acc);
}

extern "C" void kernel_launch(void* const* d_in, const int* in_sizes, int n_in,
                              void* d_out, int out_size, void* d_ws, size_t ws_size,
                              hipStream_t stream) {
    const float* x1     = (const float*)d_in[0];
    const int*   ei1    = (const int*)d_in[1];
    const int*   batch1 = (const int*)d_in[2];
    const float* x2     = (const float*)d_in[3];
    const int*   ei2    = (const int*)d_in[4];
    const int*   batch2 = (const int*)d_in[5];
    const float* W1     = (const float*)d_in[6];
    const float* b1     = (const float*)d_in[7];
    const float* W2     = (const float*)d_in[8];
    const float* b2     = (const float*)d_in[9];
    const float* W3     = (const float*)d_in[10];
    const float* b3     = (const float*)d_in[11];
    const float* Wlin   = (const float*)d_in[12];
    const float* blin   = (const float*)d_in[13];
    float* out = (float*)d_out;

    const int N  = in_sizes[0] / 128;
    const int E  = in_sizes[1] / 2;
    const int G  = out_size;
    const int N2 = 2 * N;
    const int NB  = (N + 127) / 128;
    const int NB2 = 2 * NB;

    char* ws = (char*)d_ws;
    size_t off = 0;
    auto alloc = [&](size_t bytes) -> char* {
        char* p = ws + off;
        off += (bytes + 255) & ~size_t(255);
        return p;
    };
    int*      chist   = (int*)alloc((size_t)NB2 * 4);
    int*      cstarts = (int*)alloc((size_t)(NB2 + 1) * 4);
    int*      ccur    = (int*)alloc((size_t)NB2 * 4);
    unsigned* epack   = (unsigned*)alloc((size_t)2 * E * 4);
    int*      esrc    = (int*)alloc((size_t)2 * E * 4);
    int*      starts  = (int*)alloc((size_t)(N2 + 1) * 4);
    float*    dinv    = (float*)alloc((size_t)N2 * 4);
    float*    B       = (float*)alloc((size_t)N2 * 128 * 4);
    float*    C       = (float*)alloc((size_t)N2 * 128 * 4);
    float*    pooled  = (float*)alloc((size_t)2 * G * 128 * 4);
    float*    cnt     = (float*)alloc((size_t)2 * G * 4);
    float*    e       = (float*)alloc((size_t)2 * G * 64 * 4);

    const int bP    = (E + ECHUNK - 1) / ECHUNK;
    const int bM    = (N + 63) / 64;                  // gemm blocks (one branch)
    const int nGB5  = (N * 32 + 511) / 512;           // gather blocks in combo (512 thr)
    const int nGB   = (N * 32 + 255) / 256;           // standalone gather blocks (256 thr)
    const int bPool = (((N2 + 15) / 16) * 32 + 255) / 256;
    const float* Cb = C + (size_t)N * 128;            // branch-B half of C

    // ---- CSR build (both branches fused) ----
    hipMemsetAsync(chist, 0, (size_t)NB2 * 4, stream);
    coarse_hist_kernel<<<dim3(bP, 2), 256, 0, stream>>>(ei1, ei2, chist, E, NB);
    coarse_scan_kernel<<<1, 256, 0, stream>>>(chist, cstarts, ccur, NB2);
    partition_kernel<<<dim3(bP, 2), 256, 0, stream>>>(ei1, ei2, ccur, epack, E, NB);
    fine_sort_kernel<<<NB2, 256, 0, stream>>>(epack, cstarts, esrc, starts, dinv, N, NB, NB2);

    // ---- software-pipelined branches: gather(X) ∥ gemm(Y) per launch ----
    // L1-A gemm
    gemm128_kernel<false><<<dim3(bM, 1), 512, 0, stream>>>(x1, x1, W1, nullptr, dinv, B, N);
    // gather L1-A ∥ gemm L1-B
    combo_kernel<false><<<bM + nGB5, 512, 0, stream>>>(B, esrc, starts, dinv, C, 0, N,
                                                       x2, W1, nullptr, B, N, N, bM);
    // gather L1-B ∥ gemm L2-A
    combo_kernel<true><<<bM + nGB5, 512, 0, stream>>>(B, esrc, starts, dinv, C, N, N,
                                                      C, W2, b1, B, 0, N, bM);
    // gather L2-A ∥ gemm L2-B
    combo_kernel<true><<<bM + nGB5, 512, 0, stream>>>(B, esrc, starts, dinv, C, 0, N,
                                                      Cb, W2, b1, B, N, N, bM);
    // gather L2-B ∥ gemm L3-A
    combo_kernel<true><<<bM + nGB5, 512, 0, stream>>>(B, esrc, starts, dinv, C, N, N,
                                                      C, W3, b2, B, 0, N, bM);
    // gather L3-A ∥ gemm L3-B
    combo_kernel<true><<<bM + nGB5, 512, 0, stream>>>(B, esrc, starts, dinv, C, 0, N,
                                                      Cb, W3, b2, B, N, N, bM);
    // gather L3-B
    gather_kernel<<<nGB, 256, 0, stream>>>(B, esrc, starts, dinv, C, N, N);

    // ---- mean pool + final linear + distance ----
    hipMemsetAsync(pooled, 0, (size_t)2 * G * 128 * 4, stream);
    pool_kernel<<<bPool, 256, 0, stream>>>(C, batch1, batch2, pooled, N, N2, G);
    cnt_kernel<<<(2 * G + 255) / 256, 256, 0, stream>>>(batch1, batch2, cnt, N, G);
    final_kernel<<<2 * G, 64, 0, stream>>>(pooled, cnt, b3, Wlin, blin, e);
    dist_kernel<<<(G + 255) / 256, 256, 0, stream>>>(e, e + (size_t)G * 64, out, G);
}

// Round 11
// 1079.089 us; speedup vs baseline: 1.0089x; 1.0089x over previous
//
#include <hip/hip_runtime.h>

#define EPSV 1e-6f
#define NBMAX 512      // per-branch coarse buckets (128 nodes each) — N <= 65536
#define ECHUNK 4096    // edges per block in P1/P3

// ---------------- P1: coarse histogram by dst>>7, both branches (blockIdx.y) ----------------
__global__ __launch_bounds__(256) void coarse_hist_kernel(
    const int* __restrict__ ei1, const int* __restrict__ ei2,
    int* __restrict__ chist, int E, int NB) {
    __shared__ int lh[NBMAX];
    int t = threadIdx.x;
    int branch = blockIdx.y;
    const int* dst = (branch ? ei2 : ei1) + E;
    for (int i = t; i < NB; i += 256) lh[i] = 0;
    __syncthreads();
    int base = blockIdx.x * ECHUNK;
    int end = min(base + ECHUNK, E);
    for (int i = base + t; i < end; i += 256) atomicAdd(&lh[dst[i] >> 7], 1);
    __syncthreads();
    int* gh = chist + branch * NB;
    for (int i = t; i < NB; i += 256)
        if (lh[i]) atomicAdd(&gh[i], lh[i]);
}

// ---------------- P2: scan of combined hist (NB2 <= 1024), 1 block, 4/thread ----------------
__global__ __launch_bounds__(256) void coarse_scan_kernel(
    const int* __restrict__ chist, int* __restrict__ cstarts,
    int* __restrict__ ccur, int NB2) {
    __shared__ int wt[4];
    int t = threadIdx.x, lane = t & 63, w = t >> 6;
    int base = t * 4;
    int v[4];
    int run = 0;
#pragma unroll
    for (int j = 0; j < 4; ++j) {
        v[j] = (base + j < NB2) ? chist[base + j] : 0;
        run += v[j];
    }
    int tot = run, inc = tot;
#pragma unroll
    for (int off = 1; off < 64; off <<= 1) {
        int y = __shfl_up(inc, off);
        if (lane >= off) inc += y;
    }
    if (lane == 63) wt[w] = inc;
    __syncthreads();
    int pre = 0;
    for (int ww = 0; ww < w; ++ww) pre += wt[ww];
    int excl = pre + inc - tot;
    int run2 = 0;
#pragma unroll
    for (int j = 0; j < 4; ++j) {
        if (base + j < NB2) { cstarts[base + j] = excl + run2; ccur[base + j] = excl + run2; }
        run2 += v[j];
    }
    if (t == 0) cstarts[NB2] = wt[0] + wt[1] + wt[2] + wt[3];
}

// ---------------- P3: partition edges into coarse buckets (packed src|dstlow) ----------------
__global__ __launch_bounds__(256) void partition_kernel(
    const int* __restrict__ ei1, const int* __restrict__ ei2,
    int* __restrict__ ccur, unsigned int* __restrict__ epack, int E, int NB) {
    __shared__ int lh[NBMAX];
    __shared__ int lbase[NBMAX];
    int t = threadIdx.x;
    int branch = blockIdx.y;
    const int* src = branch ? ei2 : ei1;
    const int* dst = src + E;
    for (int i = t; i < NB; i += 256) lh[i] = 0;
    __syncthreads();
    int base = blockIdx.x * ECHUNK;
    int end = min(base + ECHUNK, E);
    for (int i = base + t; i < end; i += 256) atomicAdd(&lh[dst[i] >> 7], 1);
    __syncthreads();
    int* gc = ccur + branch * NB;
    for (int i = t; i < NB; i += 256) {
        int c = lh[i];
        lbase[i] = c ? atomicAdd(&gc[i], c) : 0;
        lh[i] = 0;   // reuse as local cursor
    }
    __syncthreads();
    for (int i = base + t; i < end; i += 256) {
        int d = dst[i];
        int b = d >> 7;
        int pos = lbase[b] + atomicAdd(&lh[b], 1);
        epack[pos] = (unsigned)src[i] | ((unsigned)(d & 127) << 16);
    }
}

// ---------------- P4: fine counting sort within bucket; emit esrc, starts, dinv ----------------
__global__ __launch_bounds__(256) void fine_sort_kernel(
    const unsigned int* __restrict__ epack, const int* __restrict__ cstarts,
    int* __restrict__ esrc, int* __restrict__ starts, float* __restrict__ dinv,
    int N, int NB, int NB2) {
    __shared__ int fh[128];
    __shared__ int fex[128];
    int b = blockIdx.x, t = threadIdx.x;
    int branch = (b >= NB) ? 1 : 0;
    int soff = branch * N;
    int s0 = cstarts[b], s1 = cstarts[b + 1];
    if (t < 128) fh[t] = 0;
    __syncthreads();
    for (int i = s0 + t; i < s1; i += 256) atomicAdd(&fh[epack[i] >> 16], 1);
    __syncthreads();
    if (t < 64) {
        int a = fh[t * 2], c = fh[t * 2 + 1];
        int tot = a + c, inc = tot;
#pragma unroll
        for (int off = 1; off < 64; off <<= 1) {
            int y = __shfl_up(inc, off);
            if (t >= off) inc += y;
        }
        int excl = inc - tot;
        fex[t * 2] = excl;
        fex[t * 2 + 1] = excl + a;
    }
    __syncthreads();
    int nb0 = (b - branch * NB) << 7;
    if (t < 128) {
        int node_local = nb0 + t;
        if (node_local < N) {
            int gnode = node_local + soff;
            starts[gnode] = s0 + fex[t];
            dinv[gnode] = 1.0f / sqrtf((float)fh[t] + 1.0f);
        }
    }
    if (b == NB2 - 1 && t == 0) starts[2 * N] = s1;
    __syncthreads();
    if (t < 128) fh[t] = fex[t];
    __syncthreads();
    for (int i = s0 + t; i < s1; i += 256) {
        unsigned p = epack[i];
        int f = (int)(p >> 16);
        int pos = s0 + atomicAdd(&fh[f], 1);
        esrc[pos] = (int)(p & 0xFFFFu) + soff;
    }
}

// ---------------- device: one node's gather (32 lanes per node, 8-way MLP) ----------------
__device__ __forceinline__ void gather_one(
    const float4* __restrict__ H4, const int* __restrict__ esrc,
    const int* __restrict__ starts, const float* __restrict__ dinv,
    float4* __restrict__ C4, int node, int lane) {
    float4 a0 = H4[node * 32 + lane];
    float4 a1 = make_float4(0.f, 0.f, 0.f, 0.f);
    float4 a2 = make_float4(0.f, 0.f, 0.f, 0.f);
    float4 a3 = make_float4(0.f, 0.f, 0.f, 0.f);
    int s0 = starts[node], s1 = starts[node + 1];
    int i = s0;
    for (; i + 8 <= s1; i += 8) {
        int e0 = esrc[i];     int e1 = esrc[i + 1];
        int e2 = esrc[i + 2]; int e3 = esrc[i + 3];
        int e4 = esrc[i + 4]; int e5 = esrc[i + 5];
        int e6 = esrc[i + 6]; int e7 = esrc[i + 7];
        float4 v0 = H4[e0 * 32 + lane];
        float4 v1 = H4[e1 * 32 + lane];
        float4 v2 = H4[e2 * 32 + lane];
        float4 v3 = H4[e3 * 32 + lane];
        float4 v4 = H4[e4 * 32 + lane];
        float4 v5 = H4[e5 * 32 + lane];
        float4 v6 = H4[e6 * 32 + lane];
        float4 v7 = H4[e7 * 32 + lane];
        a0.x += v0.x; a0.y += v0.y; a0.z += v0.z; a0.w += v0.w;
        a1.x += v1.x; a1.y += v1.y; a1.z += v1.z; a1.w += v1.w;
        a2.x += v2.x; a2.y += v2.y; a2.z += v2.z; a2.w += v2.w;
        a3.x += v3.x; a3.y += v3.y; a3.z += v3.z; a3.w += v3.w;
        a0.x += v4.x; a0.y += v4.y; a0.z += v4.z; a0.w += v4.w;
        a1.x += v5.x; a1.y += v5.y; a1.z += v5.z; a1.w += v5.w;
        a2.x += v6.x; a2.y += v6.y; a2.z += v6.z; a2.w += v6.w;
        a3.x += v7.x; a3.y += v7.y; a3.z += v7.z; a3.w += v7.w;
    }
    for (; i + 4 <= s1; i += 4) {
        int e0 = esrc[i];     int e1 = esrc[i + 1];
        int e2 = esrc[i + 2]; int e3 = esrc[i + 3];
        float4 v0 = H4[e0 * 32 + lane];
        float4 v1 = H4[e1 * 32 + lane];
        float4 v2 = H4[e2 * 32 + lane];
        float4 v3 = H4[e3 * 32 + lane];
        a0.x += v0.x; a0.y += v0.y; a0.z += v0.z; a0.w += v0.w;
        a1.x += v1.x; a1.y += v1.y; a1.z += v1.z; a1.w += v1.w;
        a2.x += v2.x; a2.y += v2.y; a2.z += v2.z; a2.w += v2.w;
        a3.x += v3.x; a3.y += v3.y; a3.z += v3.z; a3.w += v3.w;
    }
    for (; i < s1; ++i) {
        float4 v = H4[esrc[i] * 32 + lane];
        a0.x += v.x; a0.y += v.y; a0.z += v.z; a0.w += v.w;
    }
    a0.x += a1.x + a2.x + a3.x;
    a0.y += a1.y + a2.y + a3.y;
    a0.z += a1.z + a2.z + a3.z;
    a0.w += a1.w + a2.w + a3.w;
    float dd = dinv[node];
    a0.x *= dd; a0.y *= dd; a0.z *= dd; a0.w *= dd;
    C4[node * 32 + lane] = a0;
}

// ---------------- device: one block's 32x128 GEMM tile, 256 threads, 4 rows/thread ----------------
// 16 KB LDS: 8 blocks/CU x 256 thr = full occupancy even in combo.
template <bool PRE>
__device__ __forceinline__ void gemm_block(
    float* Xs, const float* __restrict__ X, const float* __restrict__ W,
    const float* __restrict__ preb, const float* __restrict__ dinvL,
    float* __restrict__ YL, int bidx, int t, int M) {
    int row0 = bidx * 32;
    for (int i = t; i < 32 * 32; i += 256) {
        int r = i >> 5;
        int gr = row0 + r;
        float4 v = make_float4(0.f, 0.f, 0.f, 0.f);
        if (gr < M) {
            v = reinterpret_cast<const float4*>(X)[gr * 32 + (i & 31)];
            if (PRE) {
                float4 bb = reinterpret_cast<const float4*>(preb)[i & 31];
                v.x = fmaxf(v.x + bb.x, 0.f);
                v.y = fmaxf(v.y + bb.y, 0.f);
                v.z = fmaxf(v.z + bb.z, 0.f);
                v.w = fmaxf(v.w + bb.w, 0.f);
            }
        }
        reinterpret_cast<float4*>(Xs)[i] = v;
    }
    __syncthreads();
    int cg = t & 31;    // col group: cols 4*cg..4*cg+3
    int rg = t >> 5;    // 0..7, rows rg*4..rg*4+3
    float acc[4][4];
#pragma unroll
    for (int r = 0; r < 4; ++r) {
        acc[r][0] = 0.f; acc[r][1] = 0.f; acc[r][2] = 0.f; acc[r][3] = 0.f;
    }
    const float* xb = &Xs[rg * 4 * 128];
    const float4* W4 = reinterpret_cast<const float4*>(W);
#pragma unroll 4
    for (int k = 0; k < 128; ++k) {
        float4 wv = W4[k * 32 + cg];
#pragma unroll
        for (int r = 0; r < 4; ++r) {
            float xv = xb[r * 128 + k];
            acc[r][0] = fmaf(xv, wv.x, acc[r][0]);
            acc[r][1] = fmaf(xv, wv.y, acc[r][1]);
            acc[r][2] = fmaf(xv, wv.z, acc[r][2]);
            acc[r][3] = fmaf(xv, wv.w, acc[r][3]);
        }
    }
#pragma unroll
    for (int r = 0; r < 4; ++r) {
        int gr = row0 + rg * 4 + r;
        if (gr < M) {
            float s = dinvL[gr];
            float4 v = make_float4(acc[r][0] * s, acc[r][1] * s,
                                   acc[r][2] * s, acc[r][3] * s);
            reinterpret_cast<float4*>(YL)[gr * 32 + cg] = v;
        }
    }
}

// ---------------- standalone GEMM (branch via blockIdx.y), 256 threads ----------------
template <bool PRE>
__global__ __launch_bounds__(256) void gemm128_kernel(
    const float* __restrict__ Xa, const float* __restrict__ Xb,
    const float* __restrict__ W, const float* __restrict__ preb,
    const float* __restrict__ dinv, float* __restrict__ Y, int M) {
    __shared__ float Xs[32 * 128];
    int branch = blockIdx.y;
    const float* X = branch ? Xb : Xa;
    int goff = branch * M;
    gemm_block<PRE>(Xs, X, W, preb, dinv + goff, Y + (size_t)goff * 128,
                    blockIdx.x, threadIdx.x, M);
}

// ---------------- standalone gather over node range [node0, node0+n) ----------------
__global__ __launch_bounds__(256) void gather_kernel(
    const float* __restrict__ H, const int* __restrict__ esrc,
    const int* __restrict__ starts, const float* __restrict__ dinv,
    float* __restrict__ C, int node0, int n) {
    int gid = blockIdx.x * blockDim.x + threadIdx.x;
    int node = node0 + (gid >> 5);
    int lane = gid & 31;
    if (node >= node0 + n) return;
    gather_one(reinterpret_cast<const float4*>(H), esrc, starts, dinv,
               reinterpret_cast<float4*>(C), node, lane);
}

// ---------------- combo: gather(branch X) ∥ gemm(branch Y), one 256-thread launch ----------------
// GEMM blocks first (few, long); gather blocks after (many, short). 16 KB LDS -> 8 blocks/CU.
template <bool PRE>
__global__ __launch_bounds__(256) void combo_kernel(
    const float* __restrict__ B, const int* __restrict__ esrc,
    const int* __restrict__ starts, const float* __restrict__ dinv,
    float* __restrict__ C, int gnode0, int Ng,
    const float* __restrict__ Xg, const float* __restrict__ W,
    const float* __restrict__ preb, float* __restrict__ Y,
    int ynode0, int M, int nGemm) {
    __shared__ float Xs[32 * 128];
    int bid = blockIdx.x;
    int t = threadIdx.x;
    if (bid < nGemm) {
        gemm_block<PRE>(Xs, Xg, W, preb, dinv + ynode0, Y + (size_t)ynode0 * 128,
                        bid, t, M);
    } else {
        int gid = (bid - nGemm) * 256 + t;
        int node = gnode0 + (gid >> 5);
        int lane = gid & 31;
        if (node < gnode0 + Ng)
            gather_one(reinterpret_cast<const float4*>(B), esrc, starts, dinv,
                       reinterpret_cast<float4*>(C), node, lane);
    }
}

// ---------------- mean pool: run-length accumulate over sorted batch, both branches ----------------
__global__ void pool_kernel(const float* __restrict__ C, const int* __restrict__ batch1,
                            const int* __restrict__ batch2, float* __restrict__ pooled,
                            int N, int n2, int G) {
    int gid = blockIdx.x * blockDim.x + threadIdx.x;
    int grp = gid >> 5;
    int lane = gid & 31;
    int n0 = grp * 16;
    if (n0 >= n2) return;
    int nend = min(n0 + 16, n2);
    int branch = (n0 >= N) ? 1 : 0;
    const int* batch = branch ? batch2 : batch1;
    int boff = branch * N;
    float* pg = pooled + (size_t)branch * G * 128;
    const float4* C4 = reinterpret_cast<const float4*>(C);
    float4 acc = make_float4(0.f, 0.f, 0.f, 0.f);
    int gcur = batch[n0 - boff];
    for (int j = n0; j < nend; ++j) {
        int g = batch[j - boff];
        if (g != gcur) {
            atomicAdd(&pg[gcur * 128 + lane * 4 + 0], acc.x);
            atomicAdd(&pg[gcur * 128 + lane * 4 + 1], acc.y);
            atomicAdd(&pg[gcur * 128 + lane * 4 + 2], acc.z);
            atomicAdd(&pg[gcur * 128 + lane * 4 + 3], acc.w);
            acc = make_float4(0.f, 0.f, 0.f, 0.f);
            gcur = g;
        }
        float4 v = C4[j * 32 + lane];
        acc.x += v.x; acc.y += v.y; acc.z += v.z; acc.w += v.w;
    }
    atomicAdd(&pg[gcur * 128 + lane * 4 + 0], acc.x);
    atomicAdd(&pg[gcur * 128 + lane * 4 + 1], acc.y);
    atomicAdd(&pg[gcur * 128 + lane * 4 + 2], acc.z);
    atomicAdd(&pg[gcur * 128 + lane * 4 + 3], acc.w);
}

// ---------------- per-graph node count via binary search, both branches ----------------
__global__ void cnt_kernel(const int* __restrict__ batch1, const int* __restrict__ batch2,
                           float* __restrict__ cnt, int n, int G) {
    int g = blockIdx.x * blockDim.x + threadIdx.x;
    if (g >= 2 * G) return;
    int branch = (g >= G) ? 1 : 0;
    int gl = g - branch * G;
    const int* batch = branch ? batch2 : batch1;
    int lo = 0, hi = n;
    while (lo < hi) { int m = (lo + hi) >> 1; if (batch[m] < gl) lo = m + 1; else hi = m; }
    int lb = lo;
    hi = n;
    while (lo < hi) { int m = (lo + hi) >> 1; if (batch[m] <= gl) lo = m + 1; else hi = m; }
    cnt[g] = (float)(lo - lb);
}

// ---------------- final linear over 2G graphs ----------------
__global__ void final_kernel(const float* __restrict__ pooled, const float* __restrict__ cnt,
                             const float* __restrict__ b3, const float* __restrict__ Wlin,
                             const float* __restrict__ blin, float* __restrict__ e) {
    int g = blockIdx.x;
    int nidx = threadIdx.x;
    float inv = 1.0f / fmaxf(cnt[g], 1.0f);
    float acc = blin[nidx];
    for (int k = 0; k < 128; ++k) {
        float xk = fmaf(pooled[g * 128 + k], inv, b3[k]);
        acc = fmaf(xk, Wlin[k * 64 + nidx], acc);
    }
    e[g * 64 + nidx] = acc;
}

// ---------------- pairwise distance ----------------
__global__ void dist_kernel(const float* __restrict__ e1, const float* __restrict__ e2,
                            float* __restrict__ out, int G) {
    int g = blockIdx.x * blockDim.x + threadIdx.x;
    if (g >= G) return;
    float acc = 0.f;
    for (int j = 0; j < 64; ++j) {
        float d = e1[g * 64 + j] - e2[g * 64 + j] + EPSV;
        acc = fmaf(d, d, acc);
    }
    out[g] = sqrtf(acc);
}

extern "C" void kernel_launch(void* const* d_in, const int* in_sizes, int n_in,
                              void* d_out, int out_size, void* d_ws, size_t ws_size,
                              hipStream_t stream) {
    const float* x1     = (const float*)d_in[0];
    const int*   ei1    = (const int*)d_in[1];
    const int*   batch1 = (const int*)d_in[2];
    const float* x2     = (const float*)d_in[3];
    const int*   ei2    = (const int*)d_in[4];
    const int*   batch2 = (const int*)d_in[5];
    const float* W1     = (const float*)d_in[6];
    const float* b1     = (const float*)d_in[7];
    const float* W2     = (const float*)d_in[8];
    const float* b2     = (const float*)d_in[9];
    const float* W3     = (const float*)d_in[10];
    const float* b3     = (const float*)d_in[11];
    const float* Wlin   = (const float*)d_in[12];
    const float* blin   = (const float*)d_in[13];
    float* out = (float*)d_out;

    const int N  = in_sizes[0] / 128;
    const int E  = in_sizes[1] / 2;
    const int G  = out_size;
    const int N2 = 2 * N;
    const int NB  = (N + 127) / 128;
    const int NB2 = 2 * NB;

    char* ws = (char*)d_ws;
    size_t off = 0;
    auto alloc = [&](size_t bytes) -> char* {
        char* p = ws + off;
        off += (bytes + 255) & ~size_t(255);
        return p;
    };
    int*      chist   = (int*)alloc((size_t)NB2 * 4);
    int*      cstarts = (int*)alloc((size_t)(NB2 + 1) * 4);
    int*      ccur    = (int*)alloc((size_t)NB2 * 4);
    unsigned* epack   = (unsigned*)alloc((size_t)2 * E * 4);
    int*      esrc    = (int*)alloc((size_t)2 * E * 4);
    int*      starts  = (int*)alloc((size_t)(N2 + 1) * 4);
    float*    dinv    = (float*)alloc((size_t)N2 * 4);
    float*    B       = (float*)alloc((size_t)N2 * 128 * 4);
    float*    C       = (float*)alloc((size_t)N2 * 128 * 4);
    float*    pooled  = (float*)alloc((size_t)2 * G * 128 * 4);
    float*    cnt     = (float*)alloc((size_t)2 * G * 4);
    float*    e       = (float*)alloc((size_t)2 * G * 64 * 4);

    const int bP    = (E + ECHUNK - 1) / ECHUNK;
    const int bM    = (N + 31) / 32;                  // gemm blocks (one branch, 32-row tiles)
    const int nGB   = (N * 32 + 255) / 256;           // gather blocks (one branch)
    const int bPool = (((N2 + 15) / 16) * 32 + 255) / 256;
    const float* Cb = C + (size_t)N * 128;            // branch-B half of C

    // ---- CSR build (both branches fused) ----
    hipMemsetAsync(chist, 0, (size_t)NB2 * 4, stream);
    coarse_hist_kernel<<<dim3(bP, 2), 256, 0, stream>>>(ei1, ei2, chist, E, NB);
    coarse_scan_kernel<<<1, 256, 0, stream>>>(chist, cstarts, ccur, NB2);
    partition_kernel<<<dim3(bP, 2), 256, 0, stream>>>(ei1, ei2, ccur, epack, E, NB);
    fine_sort_kernel<<<NB2, 256, 0, stream>>>(epack, cstarts, esrc, starts, dinv, N, NB, NB2);

    // ---- software-pipelined branches: gather(X) ∥ gemm(Y) per launch ----
    // L1-A gemm
    gemm128_kernel<false><<<dim3(bM, 1), 256, 0, stream>>>(x1, x1, W1, nullptr, dinv, B, N);
    // gather L1-A ∥ gemm L1-B
    combo_kernel<false><<<bM + nGB, 256, 0, stream>>>(B, esrc, starts, dinv, C, 0, N,
                                                      x2, W1, nullptr, B, N, N, bM);
    // gather L1-B ∥ gemm L2-A
    combo_kernel<true><<<bM + nGB, 256, 0, stream>>>(B, esrc, starts, dinv, C, N, N,
                                                     C, W2, b1, B, 0, N, bM);
    // gather L2-A ∥ gemm L2-B
    combo_kernel<true><<<bM + nGB, 256, 0, stream>>>(B, esrc, starts, dinv, C, 0, N,
                                                     Cb, W2, b1, B, N, N, bM);
    // gather L2-B ∥ gemm L3-A
    combo_kernel<true><<<bM + nGB, 256, 0, stream>>>(B, esrc, starts, dinv, C, N, N,
                                                     C, W3, b2, B, 0, N, bM);
    // gather L3-A ∥ gemm L3-B
    combo_kernel<true><<<bM + nGB, 256, 0, stream>>>(B, esrc, starts, dinv, C, 0, N,
                                                     Cb, W3, b2, B, N, N, bM);
    // gather L3-B
    gather_kernel<<<nGB, 256, 0, stream>>>(B, esrc, starts, dinv, C, N, N);

    // ---- mean pool + final linear + distance ----
    hipMemsetAsync(pooled, 0, (size_t)2 * G * 128 * 4, stream);
    pool_kernel<<<bPool, 256, 0, stream>>>(C, batch1, batch2, pooled, N, N2, G);
    cnt_kernel<<<(2 * G + 255) / 256, 256, 0, stream>>>(batch1, batch2, cnt, N, G);
    final_kernel<<<2 * G, 64, 0, stream>>>(pooled, cnt, b3, Wlin, blin, e);
    dist_kernel<<<(G + 255) / 256, 256, 0, stream>>>(e, e + (size_t)G * 64, out, G);
}

// Round 12
// 742.432 us; speedup vs baseline: 1.4664x; 1.4535x over previous
//
#include <hip/hip_runtime.h>

#define EPSV 1e-6f
#define NBMAX 512      // per-branch coarse buckets (128 nodes each) — N <= 65536
#define ECHUNK 4096    // edges per block in P1/P3

// pack two f32 into bf16 pair (round-to-nearest-even)
__device__ __forceinline__ unsigned pack_bf16x2(float a, float b) {
    unsigned ua = __float_as_uint(a);
    unsigned ub = __float_as_uint(b);
    ua = (ua + 0x7FFFu + ((ua >> 16) & 1u)) >> 16;
    ub = (ub + 0x7FFFu + ((ub >> 16) & 1u)) & 0xFFFF0000u;
    return ua | ub;
}
// unpack 4 bf16 (uint2) -> float4
__device__ __forceinline__ float4 unpack_bf16x4(uint2 q) {
    float4 r;
    r.x = __uint_as_float(q.x << 16);
    r.y = __uint_as_float(q.x & 0xFFFF0000u);
    r.z = __uint_as_float(q.y << 16);
    r.w = __uint_as_float(q.y & 0xFFFF0000u);
    return r;
}

// ---------------- P1: coarse histogram by dst>>7, both branches (blockIdx.y) ----------------
__global__ __launch_bounds__(256) void coarse_hist_kernel(
    const int* __restrict__ ei1, const int* __restrict__ ei2,
    int* __restrict__ chist, int E, int NB) {
    __shared__ int lh[NBMAX];
    int t = threadIdx.x;
    int branch = blockIdx.y;
    const int* dst = (branch ? ei2 : ei1) + E;
    for (int i = t; i < NB; i += 256) lh[i] = 0;
    __syncthreads();
    int base = blockIdx.x * ECHUNK;
    int end = min(base + ECHUNK, E);
    for (int i = base + t; i < end; i += 256) atomicAdd(&lh[dst[i] >> 7], 1);
    __syncthreads();
    int* gh = chist + branch * NB;
    for (int i = t; i < NB; i += 256)
        if (lh[i]) atomicAdd(&gh[i], lh[i]);
}

// ---------------- P2: scan of combined hist (NB2 <= 1024), 1 block, 4/thread ----------------
__global__ __launch_bounds__(256) void coarse_scan_kernel(
    const int* __restrict__ chist, int* __restrict__ cstarts,
    int* __restrict__ ccur, int NB2) {
    __shared__ int wt[4];
    int t = threadIdx.x, lane = t & 63, w = t >> 6;
    int base = t * 4;
    int v[4];
    int run = 0;
#pragma unroll
    for (int j = 0; j < 4; ++j) {
        v[j] = (base + j < NB2) ? chist[base + j] : 0;
        run += v[j];
    }
    int tot = run, inc = tot;
#pragma unroll
    for (int off = 1; off < 64; off <<= 1) {
        int y = __shfl_up(inc, off);
        if (lane >= off) inc += y;
    }
    if (lane == 63) wt[w] = inc;
    __syncthreads();
    int pre = 0;
    for (int ww = 0; ww < w; ++ww) pre += wt[ww];
    int excl = pre + inc - tot;
    int run2 = 0;
#pragma unroll
    for (int j = 0; j < 4; ++j) {
        if (base + j < NB2) { cstarts[base + j] = excl + run2; ccur[base + j] = excl + run2; }
        run2 += v[j];
    }
    if (t == 0) cstarts[NB2] = wt[0] + wt[1] + wt[2] + wt[3];
}

// ---------------- P3: partition edges into coarse buckets (packed src|dstlow) ----------------
__global__ __launch_bounds__(256) void partition_kernel(
    const int* __restrict__ ei1, const int* __restrict__ ei2,
    int* __restrict__ ccur, unsigned int* __restrict__ epack, int E, int NB) {
    __shared__ int lh[NBMAX];
    __shared__ int lbase[NBMAX];
    int t = threadIdx.x;
    int branch = blockIdx.y;
    const int* src = branch ? ei2 : ei1;
    const int* dst = src + E;
    for (int i = t; i < NB; i += 256) lh[i] = 0;
    __syncthreads();
    int base = blockIdx.x * ECHUNK;
    int end = min(base + ECHUNK, E);
    for (int i = base + t; i < end; i += 256) atomicAdd(&lh[dst[i] >> 7], 1);
    __syncthreads();
    int* gc = ccur + branch * NB;
    for (int i = t; i < NB; i += 256) {
        int c = lh[i];
        lbase[i] = c ? atomicAdd(&gc[i], c) : 0;
        lh[i] = 0;   // reuse as local cursor
    }
    __syncthreads();
    for (int i = base + t; i < end; i += 256) {
        int d = dst[i];
        int b = d >> 7;
        int pos = lbase[b] + atomicAdd(&lh[b], 1);
        epack[pos] = (unsigned)src[i] | ((unsigned)(d & 127) << 16);
    }
}

// ---------------- P4: fine counting sort within bucket; emit esrc, starts, dinv ----------------
__global__ __launch_bounds__(256) void fine_sort_kernel(
    const unsigned int* __restrict__ epack, const int* __restrict__ cstarts,
    int* __restrict__ esrc, int* __restrict__ starts, float* __restrict__ dinv,
    int N, int NB, int NB2) {
    __shared__ int fh[128];
    __shared__ int fex[128];
    int b = blockIdx.x, t = threadIdx.x;
    int branch = (b >= NB) ? 1 : 0;
    int soff = branch * N;
    int s0 = cstarts[b], s1 = cstarts[b + 1];
    if (t < 128) fh[t] = 0;
    __syncthreads();
    for (int i = s0 + t; i < s1; i += 256) atomicAdd(&fh[epack[i] >> 16], 1);
    __syncthreads();
    if (t < 64) {
        int a = fh[t * 2], c = fh[t * 2 + 1];
        int tot = a + c, inc = tot;
#pragma unroll
        for (int off = 1; off < 64; off <<= 1) {
            int y = __shfl_up(inc, off);
            if (t >= off) inc += y;
        }
        int excl = inc - tot;
        fex[t * 2] = excl;
        fex[t * 2 + 1] = excl + a;
    }
    __syncthreads();
    int nb0 = (b - branch * NB) << 7;
    if (t < 128) {
        int node_local = nb0 + t;
        if (node_local < N) {
            int gnode = node_local + soff;
            starts[gnode] = s0 + fex[t];
            dinv[gnode] = 1.0f / sqrtf((float)fh[t] + 1.0f);
        }
    }
    if (b == NB2 - 1 && t == 0) starts[2 * N] = s1;
    __syncthreads();
    if (t < 128) fh[t] = fex[t];
    __syncthreads();
    for (int i = s0 + t; i < s1; i += 256) {
        unsigned p = epack[i];
        int f = (int)(p >> 16);
        int pos = s0 + atomicAdd(&fh[f], 1);
        esrc[pos] = (int)(p & 0xFFFFu) + soff;
    }
}

// ---------------- GEMM: Y = (act(X + preb) @ W) * dinv[row]; writes f32 Y and bf16 shadow Yh ----------------
// Xs in LDS (32 KB); W read from global (L1/L2-hot, 64 KB total). Both branches via blockIdx.y.
template <bool PRE>
__global__ __launch_bounds__(256, 5) void gemm128_kernel(
    const float* __restrict__ Xa, const float* __restrict__ Xb,
    const float* __restrict__ W, const float* __restrict__ preb,
    const float* __restrict__ dinv, float* __restrict__ Y,
    uint2* __restrict__ Yh, int M) {
    __shared__ float Xs[64 * 128];    // 32 KB
    int t = threadIdx.x;
    int branch = blockIdx.y;
    const float* X = branch ? Xb : Xa;
    int goff = branch * M;
    int row0 = blockIdx.x * 64;
    for (int i = t; i < 64 * 128 / 4; i += 256) {
        int r = i >> 5;
        int gr = row0 + r;
        float4 v = make_float4(0.f, 0.f, 0.f, 0.f);
        if (gr < M) {
            v = reinterpret_cast<const float4*>(X)[gr * 32 + (i & 31)];
            if (PRE) {
                float4 bb = reinterpret_cast<const float4*>(preb)[i & 31];
                v.x = fmaxf(v.x + bb.x, 0.f);
                v.y = fmaxf(v.y + bb.y, 0.f);
                v.z = fmaxf(v.z + bb.z, 0.f);
                v.w = fmaxf(v.w + bb.w, 0.f);
            }
        }
        reinterpret_cast<float4*>(Xs)[i] = v;
    }
    __syncthreads();
    int cg = t & 31;
    int rg = t >> 5;
    float acc[8][4];
#pragma unroll
    for (int r = 0; r < 8; ++r) {
        acc[r][0] = 0.f; acc[r][1] = 0.f; acc[r][2] = 0.f; acc[r][3] = 0.f;
    }
    const float* xb = &Xs[rg * 8 * 128];
    const float4* W4 = reinterpret_cast<const float4*>(W);
#pragma unroll 4
    for (int k = 0; k < 128; ++k) {
        float4 wv = W4[k * 32 + cg];
#pragma unroll
        for (int r = 0; r < 8; ++r) {
            float xv = xb[r * 128 + k];
            acc[r][0] = fmaf(xv, wv.x, acc[r][0]);
            acc[r][1] = fmaf(xv, wv.y, acc[r][1]);
            acc[r][2] = fmaf(xv, wv.z, acc[r][2]);
            acc[r][3] = fmaf(xv, wv.w, acc[r][3]);
        }
    }
#pragma unroll
    for (int r = 0; r < 8; ++r) {
        int gr = row0 + rg * 8 + r;
        if (gr < M) {
            float s = dinv[goff + gr];
            float4 v = make_float4(acc[r][0] * s, acc[r][1] * s,
                                   acc[r][2] * s, acc[r][3] * s);
            reinterpret_cast<float4*>(Y)[(goff + gr) * 32 + cg] = v;
            uint2 h;
            h.x = pack_bf16x2(v.x, v.y);
            h.y = pack_bf16x2(v.z, v.w);
            Yh[(goff + gr) * 32 + cg] = h;
        }
    }
}

// ---------------- aggregation: C[d] = dinv[d] * (B_f32[d] + sum_in Bh_bf16[s]) ----------------
// Neighbor rows read from the 12.8 MB/branch bf16 shadow (half the bytes, 2x L2 hit rate);
// self row from f32; all accumulation f32. 8-way MLP.
__global__ __launch_bounds__(256) void gather_kernel(
    const float* __restrict__ H, const uint2* __restrict__ Hh,
    const int* __restrict__ esrc, const int* __restrict__ starts,
    const float* __restrict__ dinv, float* __restrict__ C, int n) {
    int gid = blockIdx.x * blockDim.x + threadIdx.x;
    int node = gid >> 5;
    int lane = gid & 31;
    if (node >= n) return;
    const float4* H4 = reinterpret_cast<const float4*>(H);
    float4 a0 = H4[node * 32 + lane];
    float4 a1 = make_float4(0.f, 0.f, 0.f, 0.f);
    float4 a2 = make_float4(0.f, 0.f, 0.f, 0.f);
    float4 a3 = make_float4(0.f, 0.f, 0.f, 0.f);
    int s0 = starts[node], s1 = starts[node + 1];
    int i = s0;
    for (; i + 8 <= s1; i += 8) {
        int e0 = esrc[i];     int e1 = esrc[i + 1];
        int e2 = esrc[i + 2]; int e3 = esrc[i + 3];
        int e4 = esrc[i + 4]; int e5 = esrc[i + 5];
        int e6 = esrc[i + 6]; int e7 = esrc[i + 7];
        uint2 q0 = Hh[e0 * 32 + lane];
        uint2 q1 = Hh[e1 * 32 + lane];
        uint2 q2 = Hh[e2 * 32 + lane];
        uint2 q3 = Hh[e3 * 32 + lane];
        uint2 q4 = Hh[e4 * 32 + lane];
        uint2 q5 = Hh[e5 * 32 + lane];
        uint2 q6 = Hh[e6 * 32 + lane];
        uint2 q7 = Hh[e7 * 32 + lane];
        float4 v0 = unpack_bf16x4(q0);
        float4 v1 = unpack_bf16x4(q1);
        float4 v2 = unpack_bf16x4(q2);
        float4 v3 = unpack_bf16x4(q3);
        float4 v4 = unpack_bf16x4(q4);
        float4 v5 = unpack_bf16x4(q5);
        float4 v6 = unpack_bf16x4(q6);
        float4 v7 = unpack_bf16x4(q7);
        a0.x += v0.x; a0.y += v0.y; a0.z += v0.z; a0.w += v0.w;
        a1.x += v1.x; a1.y += v1.y; a1.z += v1.z; a1.w += v1.w;
        a2.x += v2.x; a2.y += v2.y; a2.z += v2.z; a2.w += v2.w;
        a3.x += v3.x; a3.y += v3.y; a3.z += v3.z; a3.w += v3.w;
        a0.x += v4.x; a0.y += v4.y; a0.z += v4.z; a0.w += v4.w;
        a1.x += v5.x; a1.y += v5.y; a1.z += v5.z; a1.w += v5.w;
        a2.x += v6.x; a2.y += v6.y; a2.z += v6.z; a2.w += v6.w;
        a3.x += v7.x; a3.y += v7.y; a3.z += v7.z; a3.w += v7.w;
    }
    for (; i + 4 <= s1; i += 4) {
        int e0 = esrc[i];     int e1 = esrc[i + 1];
        int e2 = esrc[i + 2]; int e3 = esrc[i + 3];
        uint2 q0 = Hh[e0 * 32 + lane];
        uint2 q1 = Hh[e1 * 32 + lane];
        uint2 q2 = Hh[e2 * 32 + lane];
        uint2 q3 = Hh[e3 * 32 + lane];
        float4 v0 = unpack_bf16x4(q0);
        float4 v1 = unpack_bf16x4(q1);
        float4 v2 = unpack_bf16x4(q2);
        float4 v3 = unpack_bf16x4(q3);
        a0.x += v0.x; a0.y += v0.y; a0.z += v0.z; a0.w += v0.w;
        a1.x += v1.x; a1.y += v1.y; a1.z += v1.z; a1.w += v1.w;
        a2.x += v2.x; a2.y += v2.y; a2.z += v2.z; a2.w += v2.w;
        a3.x += v3.x; a3.y += v3.y; a3.z += v3.z; a3.w += v3.w;
    }
    for (; i < s1; ++i) {
        float4 v = unpack_bf16x4(Hh[esrc[i] * 32 + lane]);
        a0.x += v.x; a0.y += v.y; a0.z += v.z; a0.w += v.w;
    }
    a0.x += a1.x + a2.x + a3.x;
    a0.y += a1.y + a2.y + a3.y;
    a0.z += a1.z + a2.z + a3.z;
    a0.w += a1.w + a2.w + a3.w;
    float dd = dinv[node];
    a0.x *= dd; a0.y *= dd; a0.z *= dd; a0.w *= dd;
    reinterpret_cast<float4*>(C)[node * 32 + lane] = a0;
}

// ---------------- mean pool: run-length accumulate over sorted batch, both branches ----------------
__global__ void pool_kernel(const float* __restrict__ C, const int* __restrict__ batch1,
                            const int* __restrict__ batch2, float* __restrict__ pooled,
                            int N, int n2, int G) {
    int gid = blockIdx.x * blockDim.x + threadIdx.x;
    int grp = gid >> 5;
    int lane = gid & 31;
    int n0 = grp * 16;
    if (n0 >= n2) return;
    int nend = min(n0 + 16, n2);
    int branch = (n0 >= N) ? 1 : 0;
    const int* batch = branch ? batch2 : batch1;
    int boff = branch * N;
    float* pg = pooled + (size_t)branch * G * 128;
    const float4* C4 = reinterpret_cast<const float4*>(C);
    float4 acc = make_float4(0.f, 0.f, 0.f, 0.f);
    int gcur = batch[n0 - boff];
    for (int j = n0; j < nend; ++j) {
        int g = batch[j - boff];
        if (g != gcur) {
            atomicAdd(&pg[gcur * 128 + lane * 4 + 0], acc.x);
            atomicAdd(&pg[gcur * 128 + lane * 4 + 1], acc.y);
            atomicAdd(&pg[gcur * 128 + lane * 4 + 2], acc.z);
            atomicAdd(&pg[gcur * 128 + lane * 4 + 3], acc.w);
            acc = make_float4(0.f, 0.f, 0.f, 0.f);
            gcur = g;
        }
        float4 v = C4[j * 32 + lane];
        acc.x += v.x; acc.y += v.y; acc.z += v.z; acc.w += v.w;
    }
    atomicAdd(&pg[gcur * 128 + lane * 4 + 0], acc.x);
    atomicAdd(&pg[gcur * 128 + lane * 4 + 1], acc.y);
    atomicAdd(&pg[gcur * 128 + lane * 4 + 2], acc.z);
    atomicAdd(&pg[gcur * 128 + lane * 4 + 3], acc.w);
}

// ---------------- per-graph node count via binary search, both branches ----------------
__global__ void cnt_kernel(const int* __restrict__ batch1, const int* __restrict__ batch2,
                           float* __restrict__ cnt, int n, int G) {
    int g = blockIdx.x * blockDim.x + threadIdx.x;
    if (g >= 2 * G) return;
    int branch = (g >= G) ? 1 : 0;
    int gl = g - branch * G;
    const int* batch = branch ? batch2 : batch1;
    int lo = 0, hi = n;
    while (lo < hi) { int m = (lo + hi) >> 1; if (batch[m] < gl) lo = m + 1; else hi = m; }
    int lb = lo;
    hi = n;
    while (lo < hi) { int m = (lo + hi) >> 1; if (batch[m] <= gl) lo = m + 1; else hi = m; }
    cnt[g] = (float)(lo - lb);
}

// ---------------- final linear over 2G graphs ----------------
__global__ void final_kernel(const float* __restrict__ pooled, const float* __restrict__ cnt,
                             const float* __restrict__ b3, const float* __restrict__ Wlin,
                             const float* __restrict__ blin, float* __restrict__ e) {
    int g = blockIdx.x;
    int nidx = threadIdx.x;
    float inv = 1.0f / fmaxf(cnt[g], 1.0f);
    float acc = blin[nidx];
    for (int k = 0; k < 128; ++k) {
        float xk = fmaf(pooled[g * 128 + k], inv, b3[k]);
        acc = fmaf(xk, Wlin[k * 64 + nidx], acc);
    }
    e[g * 64 + nidx] = acc;
}

// ---------------- pairwise distance ----------------
__global__ void dist_kernel(const float* __restrict__ e1, const float* __restrict__ e2,
                            float* __restrict__ out, int G) {
    int g = blockIdx.x * blockDim.x + threadIdx.x;
    if (g >= G) return;
    float acc = 0.f;
    for (int j = 0; j < 64; ++j) {
        float d = e1[g * 64 + j] - e2[g * 64 + j] + EPSV;
        acc = fmaf(d, d, acc);
    }
    out[g] = sqrtf(acc);
}

extern "C" void kernel_launch(void* const* d_in, const int* in_sizes, int n_in,
                              void* d_out, int out_size, void* d_ws, size_t ws_size,
                              hipStream_t stream) {
    const float* x1     = (const float*)d_in[0];
    const int*   ei1    = (const int*)d_in[1];
    const int*   batch1 = (const int*)d_in[2];
    const float* x2     = (const float*)d_in[3];
    const int*   ei2    = (const int*)d_in[4];
    const int*   batch2 = (const int*)d_in[5];
    const float* W1     = (const float*)d_in[6];
    const float* b1     = (const float*)d_in[7];
    const float* W2     = (const float*)d_in[8];
    const float* b2     = (const float*)d_in[9];
    const float* W3     = (const float*)d_in[10];
    const float* b3     = (const float*)d_in[11];
    const float* Wlin   = (const float*)d_in[12];
    const float* blin   = (const float*)d_in[13];
    float* out = (float*)d_out;

    const int N  = in_sizes[0] / 128;
    const int E  = in_sizes[1] / 2;
    const int G  = out_size;
    const int N2 = 2 * N;
    const int NB  = (N + 127) / 128;
    const int NB2 = 2 * NB;

    char* ws = (char*)d_ws;
    size_t off = 0;
    auto alloc = [&](size_t bytes) -> char* {
        char* p = ws + off;
        off += (bytes + 255) & ~size_t(255);
        return p;
    };
    int*      chist   = (int*)alloc((size_t)NB2 * 4);
    int*      cstarts = (int*)alloc((size_t)(NB2 + 1) * 4);
    int*      ccur    = (int*)alloc((size_t)NB2 * 4);
    unsigned* epack   = (unsigned*)alloc((size_t)2 * E * 4);
    int*      esrc    = (int*)alloc((size_t)2 * E * 4);
    int*      starts  = (int*)alloc((size_t)(N2 + 1) * 4);
    float*    dinv    = (float*)alloc((size_t)N2 * 4);
    float*    B       = (float*)alloc((size_t)N2 * 128 * 4);
    uint2*    Bh      = (uint2*)alloc((size_t)N2 * 128 * 2);   // bf16 shadow of B
    float*    C       = (float*)alloc((size_t)N2 * 128 * 4);
    float*    pooled  = (float*)alloc((size_t)2 * G * 128 * 4);
    float*    cnt     = (float*)alloc((size_t)2 * G * 4);
    float*    e       = (float*)alloc((size_t)2 * G * 64 * 4);

    const int bP    = (E + ECHUNK - 1) / ECHUNK;
    const int bM    = (N + 63) / 64;                  // gemm blocks (one branch)
    const int bG32  = (N2 * 32 + 255) / 256;          // gather blocks (both branches)
    const int bPool = (((N2 + 15) / 16) * 32 + 255) / 256;

    // ---- CSR build (both branches fused) ----
    hipMemsetAsync(chist, 0, (size_t)NB2 * 4, stream);
    coarse_hist_kernel<<<dim3(bP, 2), 256, 0, stream>>>(ei1, ei2, chist, E, NB);
    coarse_scan_kernel<<<1, 256, 0, stream>>>(chist, cstarts, ccur, NB2);
    partition_kernel<<<dim3(bP, 2), 256, 0, stream>>>(ei1, ei2, ccur, epack, E, NB);
    fine_sort_kernel<<<NB2, 256, 0, stream>>>(epack, cstarts, esrc, starts, dinv, N, NB, NB2);

    // ---- layer 1 ----
    gemm128_kernel<false><<<dim3(bM, 2), 256, 0, stream>>>(x1, x2, W1, nullptr, dinv, B, Bh, N);
    gather_kernel<<<bG32, 256, 0, stream>>>(B, Bh, esrc, starts, dinv, C, N2);
    // ---- layer 2 ----
    gemm128_kernel<true><<<dim3(bM, 2), 256, 0, stream>>>(C, C + (size_t)N * 128, W2, b1, dinv, B, Bh, N);
    gather_kernel<<<bG32, 256, 0, stream>>>(B, Bh, esrc, starts, dinv, C, N2);
    // ---- layer 3 (b3 folded in after pooling) ----
    gemm128_kernel<true><<<dim3(bM, 2), 256, 0, stream>>>(C, C + (size_t)N * 128, W3, b2, dinv, B, Bh, N);
    gather_kernel<<<bG32, 256, 0, stream>>>(B, Bh, esrc, starts, dinv, C, N2);

    // ---- mean pool + final linear + distance ----
    hipMemsetAsync(pooled, 0, (size_t)2 * G * 128 * 4, stream);
    pool_kernel<<<bPool, 256, 0, stream>>>(C, batch1, batch2, pooled, N, N2, G);
    cnt_kernel<<<(2 * G + 255) / 256, 256, 0, stream>>>(batch1, batch2, cnt, N, G);
    final_kernel<<<2 * G, 64, 0, stream>>>(pooled, cnt, b3, Wlin, blin, e);
    dist_kernel<<<(G + 255) / 256, 256, 0, stream>>>(e, e + (size_t)G * 64, out, G);
}